// Round 1
// baseline (219.603 us; speedup 1.0000x reference)
//
#include <hip/hip_runtime.h>

// LWTA over groups of POOL_SIZE=4 consecutive fp32 elements.
// out[i] = in[i] if i is the FIRST max within its group of 4, else 0.
// Input: 4096x8192 fp32 (flat 33,554,432 elems). Output same shape/dtype.
//
// Memory-bound streaming op: one thread per group -> float4 load + float4 store.

__global__ __launch_bounds__(256) void lwta_kernel(const float4* __restrict__ in,
                                                   float4* __restrict__ out,
                                                   int n_groups) {
    int g = blockIdx.x * blockDim.x + threadIdx.x;
    if (g >= n_groups) return;

    float4 v = in[g];

    // First-max-index semantics (matches jnp.argmax): strict > keeps earliest.
    float m = v.x;
    int w = 0;
    if (v.y > m) { m = v.y; w = 1; }
    if (v.z > m) { m = v.z; w = 2; }
    if (v.w > m) { m = v.w; w = 3; }

    float4 o;
    o.x = (w == 0) ? v.x : 0.0f;
    o.y = (w == 1) ? v.y : 0.0f;
    o.z = (w == 2) ? v.z : 0.0f;
    o.w = (w == 3) ? v.w : 0.0f;

    out[g] = o;
}

extern "C" void kernel_launch(void* const* d_in, const int* in_sizes, int n_in,
                              void* d_out, int out_size, void* d_ws, size_t ws_size,
                              hipStream_t stream) {
    const float4* in = (const float4*)d_in[0];
    float4* out = (float4*)d_out;

    int n_elems = in_sizes[0];          // 4096*8192 = 33,554,432
    int n_groups = n_elems / 4;         // 8,388,608 groups, one float4 each

    const int block = 256;
    int grid = (n_groups + block - 1) / block;

    lwta_kernel<<<grid, block, 0, stream>>>(in, out, n_groups);
}